// Round 1
// baseline (365.202 us; speedup 1.0000x reference)
//
#include <hip/hip_runtime.h>
#include <hip/hip_bf16.h>

#define NUM_EXPERTS 8
#define MODEL_DIM 1024
#define INTER_DIM 4096
#define BM 64
#define BN 64
#define BK 32
#define LSTR 40  // LDS row stride in shorts: 80 B, 16B-aligned, conflict-friendly

typedef __attribute__((ext_vector_type(8))) short short8;
typedef __attribute__((ext_vector_type(8))) unsigned short ushort8;
typedef __attribute__((ext_vector_type(4))) float floatx4;

__device__ __forceinline__ unsigned short f2b(float f) {
  union { float f; unsigned int u; } v; v.f = f;
  unsigned int r = v.u + 0x7fffu + ((v.u >> 16) & 1u);
  return (unsigned short)(r >> 16);
}

// ---------------- router: top-2 expert ids per token ----------------
__global__ __launch_bounds__(64) void router_kernel(const float* __restrict__ x,
                                                    const float* __restrict__ gw,
                                                    int* __restrict__ eids, int T) {
  int t = blockIdx.x;
  int lane = threadIdx.x;
  float acc[NUM_EXPERTS];
#pragma unroll
  for (int e = 0; e < NUM_EXPERTS; ++e) acc[e] = 0.f;
  const float* xr = x + (size_t)t * MODEL_DIM;
#pragma unroll 4
  for (int i = lane; i < MODEL_DIM; i += 64) {
    float xv = xr[i];
#pragma unroll
    for (int e = 0; e < NUM_EXPERTS; ++e) acc[e] += xv * gw[e * MODEL_DIM + i];
  }
#pragma unroll
  for (int e = 0; e < NUM_EXPERTS; ++e) {
    float v = acc[e];
#pragma unroll
    for (int off = 32; off > 0; off >>= 1) v += __shfl_xor(v, off);
    acc[e] = v;
  }
  if (lane == 0) {
    int e0 = 0; float b0 = acc[0];
#pragma unroll
    for (int e = 1; e < NUM_EXPERTS; ++e) if (acc[e] > b0) { b0 = acc[e]; e0 = e; }
    int e1 = -1; float b1 = -3.4e38f;
#pragma unroll
    for (int e = 0; e < NUM_EXPERTS; ++e) if (e != e0 && acc[e] > b1) { b1 = acc[e]; e1 = e; }
    eids[t] = e0;        // rank-0 slot
    eids[T + t] = e1;    // rank-1 slot
  }
}

// ---------------- histogram ----------------
__global__ void hist_kernel(const int* __restrict__ eids, int* __restrict__ counts, int total) {
  int i = blockIdx.x * blockDim.x + threadIdx.x;
  if (i < total) atomicAdd(&counts[eids[i]], 1);
}

// ---------------- exclusive prefix (E=8, single thread) ----------------
__global__ void offsets_kernel(const int* __restrict__ counts, int* __restrict__ offsets,
                               int* __restrict__ cursor) {
  if (threadIdx.x == 0 && blockIdx.x == 0) {
    int s = 0;
    for (int e = 0; e < NUM_EXPERTS; ++e) { offsets[e] = s; cursor[e] = s; s += counts[e]; }
    offsets[NUM_EXPERTS] = s;
  }
}

// ---------------- scatter: build per-expert token lists ----------------
__global__ void scatter_kernel(const int* __restrict__ eids, int* __restrict__ cursor,
                               int* __restrict__ token_list, int T) {
  int i = blockIdx.x * blockDim.x + threadIdx.x;
  if (i < 2 * T) {
    int e = eids[i];
    int pos = atomicAdd(&cursor[e], 1);
    int t = (i >= T) ? (i - T) : i;
    token_list[pos] = t;
  }
}

// ---------------- grouped GEMM (UP: x@W_up -> h bf16; DOWN: h@W_down -> atomicAdd out) ----
template <bool UP>
__global__ __launch_bounds__(256) void moe_gemm(
    const float* __restrict__ W,                 // [E][K][N] fp32
    const float* __restrict__ X,                 // [T][MODEL_DIM] fp32 (UP only)
    const unsigned short* __restrict__ H,        // [2T][INTER_DIM] bf16 (DOWN only)
    unsigned short* __restrict__ Hout,           // UP output
    float* __restrict__ Out,                     // DOWN output (atomic)
    const int* __restrict__ offsets,
    const int* __restrict__ token_list) {
  constexpr int K = UP ? MODEL_DIM : INTER_DIM;
  constexpr int N = UP ? INTER_DIM : MODEL_DIM;

  const int e = blockIdx.z;
  const int off = offsets[e];
  const int cnt = offsets[e + 1] - off;
  const int m0 = blockIdx.y * BM;
  if (m0 >= cnt) return;
  const int n0 = blockIdx.x * BN;

  __shared__ unsigned short sA[BM * LSTR];
  __shared__ unsigned short sB[BN * LSTR];

  const int tid = threadIdx.x;
  const int lane = tid & 63;
  const int wave = tid >> 6;
  const int wm = wave >> 1, wn = wave & 1;

  // A staging: thread -> (row, 8-wide k chunk)
  const int ar = tid >> 2;
  const int akq = (tid & 3) * 8;
  const int arow = m0 + ar;
  const int aclamped = off + (arow < cnt ? arow : cnt - 1);
  const float* aptr_f = nullptr;
  const unsigned short* aptr_h = nullptr;
  if (UP) {
    const int a_tok = token_list[aclamped];
    aptr_f = X + (size_t)a_tok * MODEL_DIM + akq;
  } else {
    aptr_h = H + (size_t)aclamped * INTER_DIM + akq;
  }

  // B staging: thread -> (n, 8-wide k chunk); stored transposed sB[n][k]
  const int bn = tid & 63;
  const int bkb = (tid >> 6) * 8;
  const float* bptr = W + (size_t)e * K * N + (size_t)bkb * N + n0 + bn;

  floatx4 acc[2][2];
  const floatx4 zero = {0.f, 0.f, 0.f, 0.f};
  acc[0][0] = zero; acc[0][1] = zero; acc[1][0] = zero; acc[1][1] = zero;

  for (int k0 = 0; k0 < K; k0 += BK) {
    // stage A
    if (UP) {
      float4 v0 = *(const float4*)(aptr_f + k0);
      float4 v1 = *(const float4*)(aptr_f + k0 + 4);
      ushort8 sv;
      sv[0] = f2b(v0.x); sv[1] = f2b(v0.y); sv[2] = f2b(v0.z); sv[3] = f2b(v0.w);
      sv[4] = f2b(v1.x); sv[5] = f2b(v1.y); sv[6] = f2b(v1.z); sv[7] = f2b(v1.w);
      *(ushort8*)(&sA[ar * LSTR + akq]) = sv;
    } else {
      uint4 v = *(const uint4*)(aptr_h + k0);
      *(uint4*)(&sA[ar * LSTR + akq]) = v;
    }
    // stage B (transposed): 8 coalesced strided rows
    float bv[8];
#pragma unroll
    for (int j = 0; j < 8; ++j) bv[j] = bptr[(size_t)(k0 + j) * N];
    ushort8 sv;
#pragma unroll
    for (int j = 0; j < 8; ++j) sv[j] = f2b(bv[j]);
    *(ushort8*)(&sB[bn * LSTR + bkb]) = sv;

    __syncthreads();

    const int koff = (lane >> 4) * 8;
    const int fr = lane & 15;
    short8 a0 = *(const short8*)(&sA[(wm * 32 + fr) * LSTR + koff]);
    short8 a1 = *(const short8*)(&sA[(wm * 32 + 16 + fr) * LSTR + koff]);
    short8 b0 = *(const short8*)(&sB[(wn * 32 + fr) * LSTR + koff]);
    short8 b1 = *(const short8*)(&sB[(wn * 32 + 16 + fr) * LSTR + koff]);
    acc[0][0] = __builtin_amdgcn_mfma_f32_16x16x32_bf16(a0, b0, acc[0][0], 0, 0, 0);
    acc[0][1] = __builtin_amdgcn_mfma_f32_16x16x32_bf16(a0, b1, acc[0][1], 0, 0, 0);
    acc[1][0] = __builtin_amdgcn_mfma_f32_16x16x32_bf16(a1, b0, acc[1][0], 0, 0, 0);
    acc[1][1] = __builtin_amdgcn_mfma_f32_16x16x32_bf16(a1, b1, acc[1][1], 0, 0, 0);

    __syncthreads();
  }

  // epilogue: C/D layout col=lane&15, row=(lane>>4)*4+j  [verified m89/m91]
  const int rbase = wm * 32 + (lane >> 4) * 4;
  const int cbase = wn * 32 + (lane & 15);
#pragma unroll
  for (int fm = 0; fm < 2; ++fm) {
#pragma unroll
    for (int fn = 0; fn < 2; ++fn) {
#pragma unroll
      for (int j = 0; j < 4; ++j) {
        const int r = rbase + fm * 16 + j;
        const int c = cbase + fn * 16;
        if (m0 + r < cnt) {
          if (UP) {
            Hout[(size_t)(off + m0 + r) * INTER_DIM + n0 + c] = f2b(acc[fm][fn][j]);
          } else {
            const int t = token_list[off + m0 + r];
            atomicAdd(&Out[(size_t)t * MODEL_DIM + n0 + c], acc[fm][fn][j]);
          }
        }
      }
    }
  }
}

extern "C" void kernel_launch(void* const* d_in, const int* in_sizes, int n_in,
                              void* d_out, int out_size, void* d_ws, size_t ws_size,
                              hipStream_t stream) {
  const float* x = (const float*)d_in[0];
  const float* gw = (const float*)d_in[1];
  const float* w_up = (const float*)d_in[2];
  const float* w_down = (const float*)d_in[3];
  float* out = (float*)d_out;

  const int T = in_sizes[0] / MODEL_DIM;  // 2048
  const int total = 2 * T;                // 4096 routed rows

  int* ws_i = (int*)d_ws;
  int* eids = ws_i;                 // [total]
  int* counts = ws_i + total;       // [8]
  int* offsets = counts + 8;        // [9]
  int* cursor = offsets + 12;       // [8]
  int* token_list = cursor + 8;     // [total]
  unsigned short* h = (unsigned short*)((char*)d_ws + (256 << 10));  // [total][INTER_DIM] bf16

  hipMemsetAsync(counts, 0, NUM_EXPERTS * sizeof(int), stream);
  hipMemsetAsync(d_out, 0, (size_t)out_size * sizeof(float), stream);

  router_kernel<<<T, 64, 0, stream>>>(x, gw, eids, T);
  hist_kernel<<<(total + 255) / 256, 256, 0, stream>>>(eids, counts, total);
  offsets_kernel<<<1, 64, 0, stream>>>(counts, offsets, cursor);
  scatter_kernel<<<(total + 255) / 256, 256, 0, stream>>>(eids, cursor, token_list, T);

  dim3 gup(INTER_DIM / BN, total / BM, NUM_EXPERTS);
  moe_gemm<true><<<gup, 256, 0, stream>>>(w_up, x, nullptr, h, nullptr, offsets, token_list);
  dim3 gdn(MODEL_DIM / BN, total / BM, NUM_EXPERTS);
  moe_gemm<false><<<gdn, 256, 0, stream>>>(w_down, nullptr, h, nullptr, out, offsets, token_list);
}

// Round 2
// 358.000 us; speedup vs baseline: 1.0201x; 1.0201x over previous
//
#include <hip/hip_runtime.h>
#include <hip/hip_bf16.h>

#define NUM_EXPERTS 8
#define MODEL_DIM 1024
#define INTER_DIM 4096
#define BM 128
#define BN 128
#define BK 32
#define LSTR 40  // LDS row stride in shorts (80 B): uniform bank depth for b128 ops

typedef __attribute__((ext_vector_type(8))) short short8;
typedef __attribute__((ext_vector_type(8))) unsigned short ushort8;
typedef __attribute__((ext_vector_type(4))) float floatx4;

__device__ __forceinline__ unsigned short f2b(float f) {
  union { float f; unsigned int u; } v; v.f = f;
  unsigned int r = v.u + 0x7fffu + ((v.u >> 16) & 1u);
  return (unsigned short)(r >> 16);
}

// ---------------- router: top-2 expert ids per token ----------------
__global__ __launch_bounds__(64) void router_kernel(const float* __restrict__ x,
                                                    const float* __restrict__ gw,
                                                    int* __restrict__ eids, int T) {
  int t = blockIdx.x;
  int lane = threadIdx.x;
  float acc[NUM_EXPERTS];
#pragma unroll
  for (int e = 0; e < NUM_EXPERTS; ++e) acc[e] = 0.f;
  const float* xr = x + (size_t)t * MODEL_DIM;
#pragma unroll 4
  for (int i = lane; i < MODEL_DIM; i += 64) {
    float xv = xr[i];
#pragma unroll
    for (int e = 0; e < NUM_EXPERTS; ++e) acc[e] += xv * gw[e * MODEL_DIM + i];
  }
#pragma unroll
  for (int e = 0; e < NUM_EXPERTS; ++e) {
    float v = acc[e];
#pragma unroll
    for (int off = 32; off > 0; off >>= 1) v += __shfl_xor(v, off);
    acc[e] = v;
  }
  if (lane == 0) {
    int e0 = 0; float b0 = acc[0];
#pragma unroll
    for (int e = 1; e < NUM_EXPERTS; ++e) if (acc[e] > b0) { b0 = acc[e]; e0 = e; }
    int e1 = -1; float b1 = -3.4e38f;
#pragma unroll
    for (int e = 0; e < NUM_EXPERTS; ++e) if (e != e0 && acc[e] > b1) { b1 = acc[e]; e1 = e; }
    eids[t] = e0;        // rank-0 slot
    eids[T + t] = e1;    // rank-1 slot
  }
}

// ---------------- histogram ----------------
__global__ void hist_kernel(const int* __restrict__ eids, int* __restrict__ counts, int total) {
  int i = blockIdx.x * blockDim.x + threadIdx.x;
  if (i < total) atomicAdd(&counts[eids[i]], 1);
}

// ---------------- exclusive prefix (E=8, single thread) ----------------
__global__ void offsets_kernel(const int* __restrict__ counts, int* __restrict__ offsets,
                               int* __restrict__ cursor) {
  if (threadIdx.x == 0 && blockIdx.x == 0) {
    int s = 0;
    for (int e = 0; e < NUM_EXPERTS; ++e) { offsets[e] = s; cursor[e] = s; s += counts[e]; }
    offsets[NUM_EXPERTS] = s;
  }
}

// ---------------- scatter: build per-expert token lists ----------------
__global__ void scatter_kernel(const int* __restrict__ eids, int* __restrict__ cursor,
                               int* __restrict__ token_list, int T) {
  int i = blockIdx.x * blockDim.x + threadIdx.x;
  if (i < 2 * T) {
    int e = eids[i];
    int pos = atomicAdd(&cursor[e], 1);
    int t = (i >= T) ? (i - T) : i;
    token_list[pos] = t;
  }
}

// ---------------- grouped GEMM, 128x128 tile, reg-prefetch double-buffer ----------
// UP:   h[row][n]  = x[token[row]][k] @ W_up[e][k][n]   (fp32 in, bf16 out)
// DOWN: out[token] += h[row][k] @ W_down[e][k][n]        (bf16 in, atomic fp32 out), split-K=4
template <bool UP>
__global__ __launch_bounds__(256) void moe_gemm(
    const float* __restrict__ W,                 // [E][K][N] fp32
    const float* __restrict__ X,                 // [T][MODEL_DIM] fp32 (UP)
    const unsigned short* __restrict__ H,        // [2T][INTER_DIM] bf16 (DOWN)
    unsigned short* __restrict__ Hout,           // UP output
    float* __restrict__ Out,                     // DOWN output (atomic)
    const int* __restrict__ offsets,
    const int* __restrict__ token_list) {
  constexpr int K = UP ? MODEL_DIM : INTER_DIM;
  constexpr int N = UP ? INTER_DIM : MODEL_DIM;
  constexpr int KCH = 1024;  // per-block K chunk (UP: full K; DOWN: K/4)

  const int zz = blockIdx.z;
  const int e = UP ? zz : (zz >> 2);
  const int kbeg = UP ? 0 : (zz & 3) * KCH;
  const int kend = kbeg + KCH;

  const int off = offsets[e];
  const int cnt = offsets[e + 1] - off;
  const int m0 = blockIdx.y * BM;
  if (m0 >= cnt) return;
  const int n0 = blockIdx.x * BN;

  __shared__ unsigned short sA[BM * LSTR];
  __shared__ unsigned short sB[BN * LSTR];

  const int tid = threadIdx.x;
  const int lane = tid & 63;
  const int wave = tid >> 6;
  const int wm = wave >> 1, wn = wave & 1;

  // ---- A staging ids: 2 threads per row, 16 k-elems each ----
  const int ar = tid >> 1;
  const int akh = (tid & 1) * 16;
  const int arow = m0 + ar;
  const int aclamped = off + (arow < cnt ? arow : cnt - 1);
  const float* aptr_f = nullptr;
  const unsigned short* aptr_h = nullptr;
  if (UP) {
    aptr_f = X + (size_t)token_list[aclamped] * MODEL_DIM + akh;
  } else {
    aptr_h = H + (size_t)aclamped * INTER_DIM + akh;
  }

  // ---- B staging ids: thread -> (n, 16 k-elems); stored transposed sB[n][k] ----
  const int bn = tid & 127;
  const int bks = (tid >> 7) * 16;
  const float* bptr = W + (size_t)e * K * N + n0 + bn;

  floatx4 acc[4][4];
  const floatx4 zero = {0.f, 0.f, 0.f, 0.f};
#pragma unroll
  for (int i = 0; i < 4; ++i)
#pragma unroll
    for (int j = 0; j < 4; ++j) acc[i][j] = zero;

  // prefetch registers
  float4 afv[4];
  uint4 ahv[2];
  float brv[16];

  auto loadA = [&](int k0) {
    if (UP) {
#pragma unroll
      for (int q = 0; q < 4; ++q) afv[q] = *(const float4*)(aptr_f + k0 + q * 4);
    } else {
      ahv[0] = *(const uint4*)(aptr_h + k0);
      ahv[1] = *(const uint4*)(aptr_h + k0 + 8);
    }
  };
  auto loadB = [&](int k0) {
#pragma unroll
    for (int j = 0; j < 16; ++j) brv[j] = bptr[(size_t)(k0 + bks + j) * N];
  };
  auto storeA = [&]() {
    if (UP) {
      ushort8 s0, s1;
#pragma unroll
      for (int q = 0; q < 4; ++q) {
        unsigned short b0 = f2b(afv[q].x), b1 = f2b(afv[q].y), b2 = f2b(afv[q].z), b3 = f2b(afv[q].w);
        if (q < 2) { s0[q*4+0]=b0; s0[q*4+1]=b1; s0[q*4+2]=b2; s0[q*4+3]=b3; }
        else       { s1[(q-2)*4+0]=b0; s1[(q-2)*4+1]=b1; s1[(q-2)*4+2]=b2; s1[(q-2)*4+3]=b3; }
      }
      *(ushort8*)(&sA[ar * LSTR + akh]) = s0;
      *(ushort8*)(&sA[ar * LSTR + akh + 8]) = s1;
    } else {
      *(uint4*)(&sA[ar * LSTR + akh]) = ahv[0];
      *(uint4*)(&sA[ar * LSTR + akh + 8]) = ahv[1];
    }
  };
  auto storeB = [&]() {
    ushort8 s0, s1;
#pragma unroll
    for (int j = 0; j < 8; ++j) s0[j] = f2b(brv[j]);
#pragma unroll
    for (int j = 0; j < 8; ++j) s1[j] = f2b(brv[8 + j]);
    *(ushort8*)(&sB[bn * LSTR + bks]) = s0;
    *(ushort8*)(&sB[bn * LSTR + bks + 8]) = s1;
  };

  loadA(kbeg);
  loadB(kbeg);

  for (int k0 = kbeg; k0 < kend; k0 += BK) {
    storeA();
    storeB();
    __syncthreads();

    if (k0 + BK < kend) {  // prefetch next K-step while computing this one
      loadA(k0 + BK);
      loadB(k0 + BK);
    }

    const int koff = (lane >> 4) * 8;
    const int fr = lane & 15;
    short8 a[4], b[4];
#pragma unroll
    for (int i = 0; i < 4; ++i)
      a[i] = *(const short8*)(&sA[(wm * 64 + i * 16 + fr) * LSTR + koff]);
#pragma unroll
    for (int j = 0; j < 4; ++j)
      b[j] = *(const short8*)(&sB[(wn * 64 + j * 16 + fr) * LSTR + koff]);
#pragma unroll
    for (int i = 0; i < 4; ++i)
#pragma unroll
      for (int j = 0; j < 4; ++j)
        acc[i][j] = __builtin_amdgcn_mfma_f32_16x16x32_bf16(a[i], b[j], acc[i][j], 0, 0, 0);

    __syncthreads();
  }

  // epilogue: C/D layout col=lane&15, row=(lane>>4)*4+j
  const int rbase = wm * 64 + (lane >> 4) * 4;
  const int cbase = wn * 64 + (lane & 15);
#pragma unroll
  for (int fm = 0; fm < 4; ++fm) {
#pragma unroll
    for (int fn = 0; fn < 4; ++fn) {
#pragma unroll
      for (int j = 0; j < 4; ++j) {
        const int r = rbase + fm * 16 + j;
        const int c = cbase + fn * 16;
        if (m0 + r < cnt) {
          if (UP) {
            Hout[(size_t)(off + m0 + r) * INTER_DIM + n0 + c] = f2b(acc[fm][fn][j]);
          } else {
            const int t = token_list[off + m0 + r];
            atomicAdd(&Out[(size_t)t * MODEL_DIM + n0 + c], acc[fm][fn][j]);
          }
        }
      }
    }
  }
}

extern "C" void kernel_launch(void* const* d_in, const int* in_sizes, int n_in,
                              void* d_out, int out_size, void* d_ws, size_t ws_size,
                              hipStream_t stream) {
  const float* x = (const float*)d_in[0];
  const float* gw = (const float*)d_in[1];
  const float* w_up = (const float*)d_in[2];
  const float* w_down = (const float*)d_in[3];
  float* out = (float*)d_out;

  const int T = in_sizes[0] / MODEL_DIM;  // 2048
  const int total = 2 * T;                // 4096 routed rows

  int* ws_i = (int*)d_ws;
  int* eids = ws_i;                 // [total]
  int* counts = ws_i + total;       // [8]
  int* offsets = counts + 8;        // [9]
  int* cursor = offsets + 12;       // [8]
  int* token_list = cursor + 8;     // [total]
  unsigned short* h = (unsigned short*)((char*)d_ws + (256 << 10));  // [total][INTER_DIM] bf16

  hipMemsetAsync(counts, 0, NUM_EXPERTS * sizeof(int), stream);
  hipMemsetAsync(d_out, 0, (size_t)out_size * sizeof(float), stream);

  router_kernel<<<T, 64, 0, stream>>>(x, gw, eids, T);
  hist_kernel<<<(total + 255) / 256, 256, 0, stream>>>(eids, counts, total);
  offsets_kernel<<<1, 64, 0, stream>>>(counts, offsets, cursor);
  scatter_kernel<<<(total + 255) / 256, 256, 0, stream>>>(eids, cursor, token_list, T);

  dim3 gup(INTER_DIM / BN, total / BM, NUM_EXPERTS);
  moe_gemm<true><<<gup, 256, 0, stream>>>(w_up, x, nullptr, h, nullptr, offsets, token_list);
  dim3 gdn(MODEL_DIM / BN, total / BM, NUM_EXPERTS * 4);  // split-K=4 for occupancy
  moe_gemm<false><<<gdn, 256, 0, stream>>>(w_down, nullptr, h, nullptr, out, offsets, token_list);
}

// Round 3
// 290.856 us; speedup vs baseline: 1.2556x; 1.2308x over previous
//
#include <hip/hip_runtime.h>
#include <hip/hip_bf16.h>

#define NUM_EXPERTS 8
#define MODEL_DIM 1024
#define INTER_DIM 4096
#define BM 128
#define BN 128
#define BK 32
#define LSTR 40  // LDS row stride in shorts (80 B). banks: row*20 dwords -> 2-way max (free)

typedef __attribute__((ext_vector_type(8))) short short8;
typedef __attribute__((ext_vector_type(8))) unsigned short ushort8;
typedef __attribute__((ext_vector_type(4))) float floatx4;

__device__ __forceinline__ unsigned short f2b(float f) {
  union { float f; unsigned int u; } v; v.f = f;
  unsigned int r = v.u + 0x7fffu + ((v.u >> 16) & 1u);
  return (unsigned short)(r >> 16);
}

// ---------------- router: top-2 expert ids per token ----------------
__global__ __launch_bounds__(64) void router_kernel(const float* __restrict__ x,
                                                    const float* __restrict__ gw,
                                                    int* __restrict__ eids, int T) {
  int t = blockIdx.x;
  int lane = threadIdx.x;
  float acc[NUM_EXPERTS];
#pragma unroll
  for (int e = 0; e < NUM_EXPERTS; ++e) acc[e] = 0.f;
  const float* xr = x + (size_t)t * MODEL_DIM;
#pragma unroll 4
  for (int i = lane; i < MODEL_DIM; i += 64) {
    float xv = xr[i];
#pragma unroll
    for (int e = 0; e < NUM_EXPERTS; ++e) acc[e] += xv * gw[e * MODEL_DIM + i];
  }
#pragma unroll
  for (int e = 0; e < NUM_EXPERTS; ++e) {
    float v = acc[e];
#pragma unroll
    for (int off = 32; off > 0; off >>= 1) v += __shfl_xor(v, off);
    acc[e] = v;
  }
  if (lane == 0) {
    int e0 = 0; float b0 = acc[0];
#pragma unroll
    for (int e = 1; e < NUM_EXPERTS; ++e) if (acc[e] > b0) { b0 = acc[e]; e0 = e; }
    int e1 = -1; float b1 = -3.4e38f;
#pragma unroll
    for (int e = 0; e < NUM_EXPERTS; ++e) if (e != e0 && acc[e] > b1) { b1 = acc[e]; e1 = e; }
    eids[t] = e0;
    eids[T + t] = e1;
  }
}

__global__ void hist_kernel(const int* __restrict__ eids, int* __restrict__ counts, int total) {
  int i = blockIdx.x * blockDim.x + threadIdx.x;
  if (i < total) atomicAdd(&counts[eids[i]], 1);
}

__global__ void offsets_kernel(const int* __restrict__ counts, int* __restrict__ offsets,
                               int* __restrict__ cursor) {
  if (threadIdx.x == 0 && blockIdx.x == 0) {
    int s = 0;
    for (int e = 0; e < NUM_EXPERTS; ++e) { offsets[e] = s; cursor[e] = s; s += counts[e]; }
    offsets[NUM_EXPERTS] = s;
  }
}

__global__ void scatter_kernel(const int* __restrict__ eids, int* __restrict__ cursor,
                               int* __restrict__ token_list, int T) {
  int i = blockIdx.x * blockDim.x + threadIdx.x;
  if (i < 2 * T) {
    int e = eids[i];
    int pos = atomicAdd(&cursor[e], 1);
    int t = (i >= T) ? (i - T) : i;
    token_list[pos] = t;
  }
}

// ---- staging macros: straight-line, named registers only (spill-proof) ----
#define A_LOAD_UP(kk)                       \
  xa0 = *(const float4*)(aptr_f + (kk));    \
  xa1 = *(const float4*)(aptr_f + (kk) + 4);\
  xa2 = *(const float4*)(aptr_f + (kk) + 8);\
  xa3 = *(const float4*)(aptr_f + (kk) + 12);

#define A_LOAD_DN(kk)                       \
  ha0 = *(const uint4*)(aptr_h + (kk));     \
  ha1 = *(const uint4*)(aptr_h + (kk) + 8);

#define A_STORE_UP(buf) {                                            \
  ushort8 s0, s1;                                                    \
  s0[0]=f2b(xa0.x); s0[1]=f2b(xa0.y); s0[2]=f2b(xa0.z); s0[3]=f2b(xa0.w); \
  s0[4]=f2b(xa1.x); s0[5]=f2b(xa1.y); s0[6]=f2b(xa1.z); s0[7]=f2b(xa1.w); \
  s1[0]=f2b(xa2.x); s1[1]=f2b(xa2.y); s1[2]=f2b(xa2.z); s1[3]=f2b(xa2.w); \
  s1[4]=f2b(xa3.x); s1[5]=f2b(xa3.y); s1[6]=f2b(xa3.z); s1[7]=f2b(xa3.w); \
  *(ushort8*)(&(buf)[ar * LSTR + akh]) = s0;                         \
  *(ushort8*)(&(buf)[ar * LSTR + akh + 8]) = s1;                     \
}

#define A_STORE_DN(buf) {                                            \
  *(uint4*)(&(buf)[ar * LSTR + akh]) = ha0;                          \
  *(uint4*)(&(buf)[ar * LSTR + akh + 8]) = ha1;                      \
}

#define B_LOAD(kk) {                                                 \
  const float* bp = bptr + (size_t)((kk) + bks) * N;                 \
  wb0 = bp[0];            wb1 = bp[(size_t)1 * N];                   \
  wb2 = bp[(size_t)2 * N];  wb3 = bp[(size_t)3 * N];                 \
  wb4 = bp[(size_t)4 * N];  wb5 = bp[(size_t)5 * N];                 \
  wb6 = bp[(size_t)6 * N];  wb7 = bp[(size_t)7 * N];                 \
  wb8 = bp[(size_t)8 * N];  wb9 = bp[(size_t)9 * N];                 \
  wb10 = bp[(size_t)10 * N]; wb11 = bp[(size_t)11 * N];              \
  wb12 = bp[(size_t)12 * N]; wb13 = bp[(size_t)13 * N];              \
  wb14 = bp[(size_t)14 * N]; wb15 = bp[(size_t)15 * N];              \
}

#define B_STORE(buf) {                                               \
  ushort8 s0, s1;                                                    \
  s0[0]=f2b(wb0);  s0[1]=f2b(wb1);  s0[2]=f2b(wb2);  s0[3]=f2b(wb3); \
  s0[4]=f2b(wb4);  s0[5]=f2b(wb5);  s0[6]=f2b(wb6);  s0[7]=f2b(wb7); \
  s1[0]=f2b(wb8);  s1[1]=f2b(wb9);  s1[2]=f2b(wb10); s1[3]=f2b(wb11);\
  s1[4]=f2b(wb12); s1[5]=f2b(wb13); s1[6]=f2b(wb14); s1[7]=f2b(wb15);\
  *(ushort8*)(&(buf)[bn * LSTR + bks]) = s0;                         \
  *(ushort8*)(&(buf)[bn * LSTR + bks + 8]) = s1;                     \
}

// ---------------- grouped GEMM, 128x128 tile, LDS double-buffer ----------
// UP:   h[row][n]  = bf16(x[token[row]]) @ bf16(W_up[e])    (fp32 in, bf16 out)
// DOWN: out[token] += h[row] @ bf16(W_down[e])              (bf16 in, atomic fp32 out), split-K=4
template <bool UP>
__global__ __launch_bounds__(256, 2) void moe_gemm(
    const float* __restrict__ W,
    const float* __restrict__ X,
    const unsigned short* __restrict__ H,
    unsigned short* __restrict__ Hout,
    float* __restrict__ Out,
    const int* __restrict__ offsets,
    const int* __restrict__ token_list) {
  constexpr int K = UP ? MODEL_DIM : INTER_DIM;
  constexpr int N = UP ? INTER_DIM : MODEL_DIM;
  constexpr int KCH = 1024;  // per-block K chunk (UP: full K; DOWN: K/4)

  const int zz = blockIdx.z;
  const int e = UP ? zz : (zz >> 2);
  const int kbeg = UP ? 0 : (zz & 3) * KCH;
  const int kend = kbeg + KCH;

  const int off = offsets[e];
  const int cnt = offsets[e + 1] - off;
  const int m0 = blockIdx.y * BM;
  if (m0 >= cnt) return;
  const int n0 = blockIdx.x * BN;

  __shared__ unsigned short sA[2][BM * LSTR];
  __shared__ unsigned short sB[2][BN * LSTR];

  const int tid = threadIdx.x;
  const int lane = tid & 63;
  const int wave = tid >> 6;
  const int wm = wave >> 1, wn = wave & 1;

  // A staging ids: 2 threads per row, 16 k-elems each
  const int ar = tid >> 1;
  const int akh = (tid & 1) * 16;
  const int arow = m0 + ar;
  const int aclamped = off + (arow < cnt ? arow : cnt - 1);
  const float* aptr_f = nullptr;
  const unsigned short* aptr_h = nullptr;
  if (UP) {
    aptr_f = X + (size_t)token_list[aclamped] * MODEL_DIM + akh;
  } else {
    aptr_h = H + (size_t)aclamped * INTER_DIM + akh;
  }

  // B staging ids: thread -> (n, 16 k-elems); stored transposed sB[n][k]
  const int bn = tid & 127;
  const int bks = (tid >> 7) * 16;
  const float* bptr = W + (size_t)e * K * N + n0 + bn;

  floatx4 acc[4][4];
  const floatx4 zero = {0.f, 0.f, 0.f, 0.f};
#pragma unroll
  for (int i = 0; i < 4; ++i)
#pragma unroll
    for (int j = 0; j < 4; ++j) acc[i][j] = zero;

  // named prefetch registers
  float4 xa0, xa1, xa2, xa3;
  uint4 ha0, ha1;
  float wb0, wb1, wb2, wb3, wb4, wb5, wb6, wb7;
  float wb8, wb9, wb10, wb11, wb12, wb13, wb14, wb15;

  // prologue: stage first K-step into buffer 0
  if (UP) { A_LOAD_UP(kbeg); } else { A_LOAD_DN(kbeg); }
  B_LOAD(kbeg);
  if (UP) { A_STORE_UP(sA[0]); } else { A_STORE_DN(sA[0]); }
  B_STORE(sB[0]);
  __syncthreads();

  int cur = 0;
  for (int k0 = kbeg; k0 < kend; k0 += BK) {
    const bool has_next = (k0 + BK < kend);
    if (has_next) {  // issue next-tile loads; latency hides under MFMA below
      if (UP) { A_LOAD_UP(k0 + BK); } else { A_LOAD_DN(k0 + BK); }
      B_LOAD(k0 + BK);
    }

    const unsigned short* rA = sA[cur];
    const unsigned short* rB = sB[cur];
    const int koff = (lane >> 4) * 8;
    const int fr = lane & 15;
    short8 a[4], b[4];
#pragma unroll
    for (int i = 0; i < 4; ++i)
      a[i] = *(const short8*)(&rA[(wm * 64 + i * 16 + fr) * LSTR + koff]);
#pragma unroll
    for (int j = 0; j < 4; ++j)
      b[j] = *(const short8*)(&rB[(wn * 64 + j * 16 + fr) * LSTR + koff]);
#pragma unroll
    for (int i = 0; i < 4; ++i)
#pragma unroll
      for (int j = 0; j < 4; ++j)
        acc[i][j] = __builtin_amdgcn_mfma_f32_16x16x32_bf16(a[i], b[j], acc[i][j], 0, 0, 0);

    if (has_next) {  // write other buffer (no race: one barrier/iter separates)
      if (UP) { A_STORE_UP(sA[cur ^ 1]); } else { A_STORE_DN(sA[cur ^ 1]); }
      B_STORE(sB[cur ^ 1]);
      __syncthreads();
      cur ^= 1;
    }
  }

  // epilogue: C/D layout col=lane&15, row=(lane>>4)*4+j
  const int rbase = wm * 64 + (lane >> 4) * 4;
  const int cbase = wn * 64 + (lane & 15);
#pragma unroll
  for (int fm = 0; fm < 4; ++fm) {
#pragma unroll
    for (int fn = 0; fn < 4; ++fn) {
#pragma unroll
      for (int j = 0; j < 4; ++j) {
        const int r = rbase + fm * 16 + j;
        const int c = cbase + fn * 16;
        if (m0 + r < cnt) {
          if (UP) {
            Hout[(size_t)(off + m0 + r) * INTER_DIM + n0 + c] = f2b(acc[fm][fn][j]);
          } else {
            const int t = token_list[off + m0 + r];
            atomicAdd(&Out[(size_t)t * MODEL_DIM + n0 + c], acc[fm][fn][j]);
          }
        }
      }
    }
  }
}

extern "C" void kernel_launch(void* const* d_in, const int* in_sizes, int n_in,
                              void* d_out, int out_size, void* d_ws, size_t ws_size,
                              hipStream_t stream) {
  const float* x = (const float*)d_in[0];
  const float* gw = (const float*)d_in[1];
  const float* w_up = (const float*)d_in[2];
  const float* w_down = (const float*)d_in[3];
  float* out = (float*)d_out;

  const int T = in_sizes[0] / MODEL_DIM;  // 2048
  const int total = 2 * T;                // 4096 routed rows

  int* ws_i = (int*)d_ws;
  int* eids = ws_i;                 // [total]
  int* counts = ws_i + total;       // [8]
  int* offsets = counts + 8;        // [9]
  int* cursor = offsets + 12;       // [8]
  int* token_list = cursor + 8;     // [total]
  unsigned short* h = (unsigned short*)((char*)d_ws + (256 << 10));  // [total][INTER_DIM] bf16

  hipMemsetAsync(counts, 0, NUM_EXPERTS * sizeof(int), stream);
  hipMemsetAsync(d_out, 0, (size_t)out_size * sizeof(float), stream);

  router_kernel<<<T, 64, 0, stream>>>(x, gw, eids, T);
  hist_kernel<<<(total + 255) / 256, 256, 0, stream>>>(eids, counts, total);
  offsets_kernel<<<1, 64, 0, stream>>>(counts, offsets, cursor);
  scatter_kernel<<<(total + 255) / 256, 256, 0, stream>>>(eids, cursor, token_list, T);

  dim3 gup(INTER_DIM / BN, total / BM, NUM_EXPERTS);
  moe_gemm<true><<<gup, 256, 0, stream>>>(w_up, x, nullptr, h, nullptr, offsets, token_list);
  dim3 gdn(MODEL_DIM / BN, total / BM, NUM_EXPERTS * 4);  // split-K=4 for occupancy
  moe_gemm<false><<<gdn, 256, 0, stream>>>(w_down, nullptr, h, nullptr, out, offsets, token_list);
}